// Round 4
// baseline (365.951 us; speedup 1.0000x reference)
//
#include <hip/hip_runtime.h>
#include <hip/hip_bf16.h>

#define N_NODES 65536
#define IN_CH 512
#define HIDDEN 256
#define OUT_CH 8
#define NUM_GRAPHS 32
#define MAX_LEN 4096
#define BN_EPS 1e-5f
#define BN_BLOCKS 2048

using short8  = __attribute__((ext_vector_type(8))) short;
using floatx4 = __attribute__((ext_vector_type(4))) float;
typedef unsigned int u32;
typedef unsigned short u16;

__device__ inline u16 f2b(float f) {
    u32 u = __float_as_uint(f);
    u += 0x7FFFu + ((u >> 16) & 1u);
    return (u16)(u >> 16);
}
// GELU tanh-form via hw exp+rcp; max abs err vs exact-erf ~3e-4.
__device__ inline float gelu_f(float x) {
    float z = x + 0.044715f * x * x * x;
    float e = __builtin_exp2f(-2.3022078f * z);
    return x * __builtin_amdgcn_rcpf(1.0f + e);
}
__device__ inline float tanh_f(float y) {
    y = fminf(fmaxf(y, -20.0f), 20.0f);
    float t = __builtin_exp2f(2.885390082f * y);
    return (t - 1.0f) * __builtin_amdgcn_rcpf(t + 1.0f);
}
__device__ inline void load_lds16(const void* g, void* l) {
    __builtin_amdgcn_global_load_lds(
        (const __attribute__((address_space(1))) u32*)g,
        (__attribute__((address_space(3))) u32*)l, 16, 0, 0);
}

// ---- fused: per-channel sum/sumsq partials + raw bf16 cast of x ----
__global__ __launch_bounds__(256) void statscast_k(const float* __restrict__ x,
                                                   u16* __restrict__ xb,
                                                   float4* __restrict__ partials) {
    __shared__ float4 sS[128];
    __shared__ float4 sQ[128];
    int tid = threadIdx.x;
    int half = tid >> 7;
    int c = tid & 127;
    const float4* x4 = (const float4*)x;
    uint2* xb2 = (uint2*)xb;
    float4 s = make_float4(0.f, 0.f, 0.f, 0.f);
    float4 q = make_float4(0.f, 0.f, 0.f, 0.f);
    int row0 = blockIdx.x * 32;
#pragma unroll
    for (int r = half; r < 32; r += 2) {
        size_t off = (size_t)(row0 + r) * 128 + c;
        float4 v = x4[off];
        s.x += v.x; s.y += v.y; s.z += v.z; s.w += v.w;
        q.x += v.x * v.x; q.y += v.y * v.y; q.z += v.z * v.z; q.w += v.w * v.w;
        uint2 o;
        o.x = (u32)f2b(v.x) | ((u32)f2b(v.y) << 16);
        o.y = (u32)f2b(v.z) | ((u32)f2b(v.w) << 16);
        xb2[off] = o;
    }
    if (half == 1) { sS[c] = s; sQ[c] = q; }
    __syncthreads();
    if (half == 0) {
        float4 s2 = sS[c], q2 = sQ[c];
        s.x += s2.x; s.y += s2.y; s.z += s2.z; s.w += s2.w;
        q.x += q2.x; q.y += q2.y; q.z += q2.z; q.w += q2.w;
        partials[(size_t)blockIdx.x * 256 + c * 2]     = make_float4(s.x, q.x, s.y, q.y);
        partials[(size_t)blockIdx.x * 256 + c * 2 + 1] = make_float4(s.z, q.z, s.w, q.w);
    }
}

// ---- reduce partials -> scale/shift ----
__global__ __launch_bounds__(256) void bn_reduce_k(const float4* __restrict__ partials,
                                                   const float* __restrict__ gamma,
                                                   const float* __restrict__ beta,
                                                   float* __restrict__ scale,
                                                   float* __restrict__ shift) {
    __shared__ float4 sd[256];
    int tid = threadIdx.x;
    int g = blockIdx.x;
    float4 a = make_float4(0.f, 0.f, 0.f, 0.f);
    for (int r = tid; r < BN_BLOCKS; r += 256) {
        float4 v = partials[(size_t)r * 256 + g];
        a.x += v.x; a.y += v.y; a.z += v.z; a.w += v.w;
    }
    sd[tid] = a;
    __syncthreads();
    for (int st = 128; st > 0; st >>= 1) {
        if (tid < st) {
            float4 b = sd[tid + st];
            float4 m = sd[tid];
            m.x += b.x; m.y += b.y; m.z += b.z; m.w += b.w;
            sd[tid] = m;
        }
        __syncthreads();
    }
    if (tid == 0) {
        float4 t = sd[0];
        int c0 = g * 2, c1 = g * 2 + 1;
        const float inv = 1.0f / N_NODES;
        float mu0 = t.x * inv, var0 = t.y * inv - mu0 * mu0;
        float mu1 = t.z * inv, var1 = t.w * inv - mu1 * mu1;
        float sc0 = gamma[c0] * rsqrtf(var0 + BN_EPS);
        float sc1 = gamma[c1] * rsqrtf(var1 + BN_EPS);
        scale[c0] = sc0; shift[c0] = beta[c0] - mu0 * sc0;
        scale[c1] = sc1; shift[c1] = beta[c1] - mu1 * sc1;
    }
}

// ---- prep: W transposes/casts + folded bias b1f + graph offsets + pad-fill ----
__global__ __launch_bounds__(256) void prep_k(const float* __restrict__ W1,
                                              const float* __restrict__ W2,
                                              const float* __restrict__ W3,
                                              const float* __restrict__ b1,
                                              const float* __restrict__ scale,
                                              const float* __restrict__ shift,
                                              u16* __restrict__ W1T,
                                              u16* __restrict__ W2T,
                                              u16* __restrict__ W3T,
                                              float* __restrict__ b1f,
                                              const int* __restrict__ batch,
                                              int* __restrict__ offsets,
                                              const float* __restrict__ bo,
                                              const float* __restrict__ alpha_p,
                                              const float* __restrict__ dyt_w,
                                              const float* __restrict__ dyt_b,
                                              float* __restrict__ out) {
    __shared__ int sof2[NUM_GRAPHS + 1];
    int bid = blockIdx.x;
    int tid = threadIdx.x;
    if (bid < 1792) {
        int idx = bid * 256 + tid;
        if (idx < 262144) {                       // W1 [512,512]
            int k = idx >> 9, m = idx & 511;
            W1T[(size_t)m * 512 + k] = f2b(scale[k] * W1[idx]);
        } else if (idx < 262144 + 131072) {       // W2 [512,256]
            int i = idx - 262144;
            int k = i >> 8, m = i & 255;
            W2T[(size_t)m * 512 + k] = f2b(W2[i]);
        } else {                                  // W3 [256,256]
            int i = idx - 393216;
            int k = i >> 8, m = i & 255;
            W3T[(size_t)m * 256 + k] = f2b(W3[i]);
        }
        if (bid == 0 && tid < NUM_GRAPHS + 1) {
            int gph = tid;
            int lo = 0, hi = N_NODES;
            while (lo < hi) {
                int mid = (lo + hi) >> 1;
                if (batch[mid] < gph) lo = mid + 1; else hi = mid;
            }
            offsets[gph] = lo;
        }
    } else if (bid < 1794) {
        int m = (bid - 1792) * 256 + tid;
        float acc = b1[m];
#pragma unroll 16
        for (int k = 0; k < 512; ++k) acc += shift[k] * W1[k * 512 + m];
        b1f[m] = acc;
    } else {
        // pad-slot fill: each block recomputes graph boundaries (no dependence
        // on offsets[] written by bid 0 of this same kernel)
        if (tid < NUM_GRAPHS + 1) {
            int target = tid;
            int lo = 0, hi = N_NODES;
            while (lo < hi) {
                int mid = (lo + hi) >> 1;
                if (batch[mid] < target) lo = mid + 1; else hi = mid;
            }
            sof2[tid] = lo;
        }
        __syncthreads();
        int idx = (bid - 1794) * 256 + tid;       // 512 blocks -> 131072 slots
        int g = idx & 31;
        int p = idx >> 5;
        if (p >= sof2[g + 1] - sof2[g]) {
            float alpha = alpha_p[0];
            float rv[8];
#pragma unroll
            for (int c = 0; c < 8; ++c) {
                float a = gelu_f(bo[c]);
                a = dyt_w[c] * tanh_f(alpha * a) + dyt_b[c];
                rv[c] = tanh_f(a);
            }
            float4* o = (float4*)(out + (size_t)idx * OUT_CH);
            o[0] = make_float4(rv[0], rv[1], rv[2], rv[3]);
            o[1] = make_float4(rv[4], rv[5], rv[6], rv[7]);
        }
    }
}

// ---------------- GEMM1: 8-phase counted-vmcnt pipeline (A/B vs 2-phase) ----------------
// 256x256 tile, 512 threads (8 waves, 2 row x 4 col), BK=64, double-buffered
// LDS (128 KiB, 1 blk/CU). Per phase: {ds_read subtile || 2 global_load_lds of
// tile t+1 || barrier || setprio(1) 16 MFMA setprio(0) || barrier}. One
// s_waitcnt vmcnt(2) per K-step -- load queue never drains to 0 in the loop.
// k-accumulation order identical to the 2-phase kernel -> bit-identical C.
#define FENCE asm volatile("" ::: "memory")

template <int DO_GELU, int NXB>
__global__ __launch_bounds__(512, 2) void gemm_bt8_k(const u16* __restrict__ A,
                                                     const u16* __restrict__ BT,
                                                     const float* __restrict__ bias,
                                                     u16* __restrict__ C,
                                                     int K, int M) {
    __shared__ __align__(16) u16 As[2][256 * 64];   // 2 x 32KB
    __shared__ __align__(16) u16 Bs[2][256 * 64];   // 2 x 32KB
    int tid = threadIdx.x;
    int lane = tid & 63;
    int bid = blockIdx.x;
    int xcd = bid & 7;
    int slot = bid >> 3;
    int rloc = slot / NXB;
    int colb = slot - rloc * NXB;
    int row0 = (xcd * 32 + rloc) * 256;
    int col0 = colb * 256;
    int wave = tid >> 6;
    int wr = (wave >> 2) * 128;    // 0/128
    int wc = (wave & 3) * 64;      // 0..192
    int l15 = lane & 15;
    int q = lane >> 4;

    floatx4 acc[8][4] = {};

    const u16* pA[4];
    const u16* pB[4];
    int ldst[4];
#pragma unroll
    for (int s = 0; s < 4; ++s) {
        int li = s * 512 + tid;
        int r = li >> 3;
        int g = li & 7;
        int gs = g ^ (r & 7);                    // pre-swizzled global source
        pA[s] = A + (size_t)(row0 + r) * K + gs * 8;
        pB[s] = BT + (size_t)(col0 + r) * K + gs * 8;
        ldst[s] = li * 8;                        // linear LDS dest
    }

#define LOAD_AF(BASE, GIDX)                                                    \
    _Pragma("unroll")                                                          \
    for (int i = 0; i < 4; ++i) {                                              \
        int row = (BASE) + i * 16 + l15;                                       \
        af[i] = *(const short8*)&As[cur][row * 64 + ((GIDX) ^ (row & 7)) * 8]; \
    }
#define LOAD_BG(BASE, GIDX)                                                    \
    _Pragma("unroll")                                                          \
    for (int j = 0; j < 4; ++j) {                                              \
        int row = (BASE) + j * 16 + l15;                                       \
        bg[j] = *(const short8*)&Bs[cur][row * 64 + ((GIDX) ^ (row & 7)) * 8]; \
    }
#define MFMA16(IB)                                                             \
    __builtin_amdgcn_s_setprio(1);                                             \
    _Pragma("unroll")                                                          \
    for (int i = 0; i < 4; ++i)                                                \
        _Pragma("unroll")                                                      \
        for (int j = 0; j < 4; ++j)                                            \
            acc[(IB) + i][j] = __builtin_amdgcn_mfma_f32_16x16x32_bf16(        \
                bg[j], af[i], acc[(IB) + i][j], 0, 0, 0);                      \
    __builtin_amdgcn_s_setprio(0)

    // prologue: stage tile 0 into buf 0 (8 loads in flight)
#pragma unroll
    for (int s = 0; s < 4; ++s) load_lds16(pA[s], &As[0][ldst[s]]);
#pragma unroll
    for (int s = 0; s < 4; ++s) load_lds16(pB[s], &Bs[0][ldst[s]]);

    const int nt = K >> 6;
    for (int t = 0; t < nt; ++t) {
        const int cur = t & 1;
        const int nx = cur ^ 1;
        // last iter: dummy re-stage of tile 0 keeps the vmcnt count uniform
        const int kn = (t + 1 < nt) ? ((t + 1) << 6) : 0;
        short8 af[4], bg[4];

        // ---- phase 0: ks=0, rows 0..63 of wave tile ----
        load_lds16(pA[0] + kn, &As[nx][ldst[0]]);
        load_lds16(pA[1] + kn, &As[nx][ldst[1]]);
        asm volatile("s_waitcnt vmcnt(2)" ::: "memory");  // tile-t landed (all 8)
        __builtin_amdgcn_s_barrier();
        FENCE;
        LOAD_AF(wr, q);
        LOAD_BG(wc, q);
        MFMA16(0);
        FENCE;
        __builtin_amdgcn_s_barrier();
        // ---- phase 1: ks=0, rows 64..127 ----
        LOAD_AF(wr + 64, q);
        load_lds16(pA[2] + kn, &As[nx][ldst[2]]);
        load_lds16(pA[3] + kn, &As[nx][ldst[3]]);
        FENCE;
        __builtin_amdgcn_s_barrier();
        FENCE;
        MFMA16(4);
        FENCE;
        __builtin_amdgcn_s_barrier();
        // ---- phase 2: ks=1, rows 0..63 ----
        LOAD_AF(wr, 4 + q);
        LOAD_BG(wc, 4 + q);
        load_lds16(pB[0] + kn, &Bs[nx][ldst[0]]);
        load_lds16(pB[1] + kn, &Bs[nx][ldst[1]]);
        FENCE;
        __builtin_amdgcn_s_barrier();
        FENCE;
        MFMA16(0);
        FENCE;
        __builtin_amdgcn_s_barrier();
        // ---- phase 3: ks=1, rows 64..127 ----
        LOAD_AF(wr + 64, 4 + q);
        load_lds16(pB[2] + kn, &Bs[nx][ldst[2]]);
        load_lds16(pB[3] + kn, &Bs[nx][ldst[3]]);
        FENCE;
        __builtin_amdgcn_s_barrier();
        FENCE;
        MFMA16(4);
        FENCE;
        __builtin_amdgcn_s_barrier();
        FENCE;
    }
    // drain the dummy-stage loads before LDS goes away / epilogue stores
    asm volatile("s_waitcnt vmcnt(0)" ::: "memory");

    // epilogue: row = row0+wr+i*16+l15 ; col = col0+wc+j*16+q*4+reg
#pragma unroll
    for (int i = 0; i < 8; ++i) {
        size_t rbase = (size_t)(row0 + wr + i * 16 + l15) * M;
#pragma unroll
        for (int j = 0; j < 4; ++j) {
            int c = col0 + wc + j * 16 + q * 4;
            float4 b4 = *(const float4*)&bias[c];
            float v0 = acc[i][j][0] + b4.x;
            float v1 = acc[i][j][1] + b4.y;
            float v2 = acc[i][j][2] + b4.z;
            float v3 = acc[i][j][3] + b4.w;
            if (DO_GELU) { v0 = gelu_f(v0); v1 = gelu_f(v1); v2 = gelu_f(v2); v3 = gelu_f(v3); }
            uint2 pk;
            pk.x = (u32)f2b(v0) | ((u32)f2b(v1) << 16);
            pk.y = (u32)f2b(v2) | ((u32)f2b(v3) << 16);
            *(uint2*)&C[rbase + c] = pk;
        }
    }
#undef LOAD_AF
#undef LOAD_BG
#undef MFMA16
}

// -------- fused GEMM2+GEMM3+HEAD: out = head(gelu(h1@W2+b2)@W3 + b3) --------
// Block owns 256 rows end-to-end. gemm2: 8-phase counted-vmcnt dbuf pipeline
// (128KB LDS). h2 tile overlays the staging dbuf. gemm3: A stationary in LDS,
// B = W3T from global (L2). h3 tile (bf16, XOR-swizzled by row&31) replaces
// the h2 tile in LDS -- NEVER goes to HBM. head: 2 threads/row x 4 channels,
// k ascending (same order + same bf16 quantization as the old head_k ->
// bit-identical out), activations, scatter to out[(p*32+g)*8].
__global__ __launch_bounds__(512, 2) void gemm23h_k(const u16* __restrict__ A,
                                                    const u16* __restrict__ B2T,
                                                    const float* __restrict__ b2v,
                                                    const u16* __restrict__ W3T,
                                                    const float* __restrict__ b3v,
                                                    const float* __restrict__ Wo,
                                                    const float* __restrict__ bo,
                                                    const int* __restrict__ offsets,
                                                    const float* __restrict__ alpha_p,
                                                    const float* __restrict__ dyt_w,
                                                    const float* __restrict__ dyt_b,
                                                    float* __restrict__ out) {
    __shared__ __align__(16) u16 lds[65536];   // 128KB: staging dbuf -> h2 tile -> h3 tile
    __shared__ float sWo[HIDDEN * OUT_CH];     // 8KB
    __shared__ int soff[NUM_GRAPHS + 1];
    int tid = threadIdx.x;
    int lane = tid & 63;
    int bid = blockIdx.x;
    int xcd = bid & 7;
    int slot = bid >> 3;
    int row0 = (xcd * 32 + slot) * 256;
    int wave = tid >> 6;
    int wr = (wave >> 2) * 128;    // 0/128
    int wc = (wave & 3) * 64;      // 0..192
    int l15 = lane & 15;
    int q = lane >> 4;

    // stage Wo + graph offsets early (consumed only in the head phase)
    ((float4*)sWo)[tid] = ((const float4*)Wo)[tid];
    if (tid < NUM_GRAPHS + 1) soff[tid] = offsets[tid];

    floatx4 acc[8][4] = {};

    const u16* pA[4];
    const u16* pB[4];
    int ldst[4];
#pragma unroll
    for (int s = 0; s < 4; ++s) {
        int li = s * 512 + tid;
        int r = li >> 3;
        int g = li & 7;
        int gs = g ^ (r & 7);                    // pre-swizzled global source
        pA[s] = A + (size_t)(row0 + r) * 512 + gs * 8;
        pB[s] = B2T + (size_t)r * 512 + gs * 8;
        ldst[s] = li * 8;                        // linear LDS dest (u16 units)
    }

#define LDA2(BASE, GIDX)                                                             \
    _Pragma("unroll")                                                                \
    for (int i = 0; i < 4; ++i) {                                                    \
        int row = (BASE) + i * 16 + l15;                                             \
        af[i] = *(const short8*)&lds[curA + row * 64 + (((GIDX) ^ (row & 7)) << 3)]; \
    }
#define LDB2(BASE, GIDX)                                                             \
    _Pragma("unroll")                                                                \
    for (int j = 0; j < 4; ++j) {                                                    \
        int row = (BASE) + j * 16 + l15;                                             \
        bg[j] = *(const short8*)&lds[curB + row * 64 + (((GIDX) ^ (row & 7)) << 3)]; \
    }
#define MFMA16(IB)                                                                   \
    __builtin_amdgcn_s_setprio(1);                                                   \
    _Pragma("unroll")                                                                \
    for (int i = 0; i < 4; ++i)                                                      \
        _Pragma("unroll")                                                            \
        for (int j = 0; j < 4; ++j)                                                  \
            acc[(IB) + i][j] = __builtin_amdgcn_mfma_f32_16x16x32_bf16(              \
                bg[j], af[i], acc[(IB) + i][j], 0, 0, 0);                            \
    __builtin_amdgcn_s_setprio(0)

    // prologue: stage tile 0 into buf 0 (8 loads in flight)
#pragma unroll
    for (int s = 0; s < 4; ++s) load_lds16(pA[s], &lds[ldst[s]]);
#pragma unroll
    for (int s = 0; s < 4; ++s) load_lds16(pB[s], &lds[32768 + ldst[s]]);

    const int nt = 8;                            // K2 = 512
    for (int t = 0; t < nt; ++t) {
        const int cur = t & 1;
        const int nx = cur ^ 1;
        const bool last = (t + 1 == nt);
        const int kn = (t + 1) << 6;
        const int curA = cur * 16384, curB = 32768 + cur * 16384;
        const int nxA = nx * 16384,  nxB = 32768 + nx * 16384;
        short8 af[4], bg[4];

        // ---- phase 0: ks=0, rows 0..63 of wave tile ----
        if (!last) {
            load_lds16(pA[0] + kn, &lds[nxA + ldst[0]]);
            load_lds16(pA[1] + kn, &lds[nxA + ldst[1]]);
        }
        if (last) asm volatile("s_waitcnt vmcnt(0)" ::: "memory");  // tile-7: drain all
        else      asm volatile("s_waitcnt vmcnt(2)" ::: "memory");  // tile-t landed, 2 in flight
        __builtin_amdgcn_s_barrier();
        FENCE;
        LDA2(wr, q);
        LDB2(wc, q);
        MFMA16(0);
        FENCE;
        __builtin_amdgcn_s_barrier();
        // ---- phase 1: ks=0, rows 64..127 ----
        LDA2(wr + 64, q);
        if (!last) {
            load_lds16(pA[2] + kn, &lds[nxA + ldst[2]]);
            load_lds16(pA[3] + kn, &lds[nxA + ldst[3]]);
        }
        FENCE;
        __builtin_amdgcn_s_barrier();
        FENCE;
        MFMA16(4);
        FENCE;
        __builtin_amdgcn_s_barrier();
        // ---- phase 2: ks=1, rows 0..63 ----
        LDA2(wr, 4 + q);
        LDB2(wc, 4 + q);
        if (!last) {
            load_lds16(pB[0] + kn, &lds[nxB + ldst[0]]);
            load_lds16(pB[1] + kn, &lds[nxB + ldst[1]]);
        }
        FENCE;
        __builtin_amdgcn_s_barrier();
        FENCE;
        MFMA16(0);
        FENCE;
        __builtin_amdgcn_s_barrier();
        // ---- phase 3: ks=1, rows 64..127 ----
        LDA2(wr + 64, 4 + q);
        if (!last) {
            load_lds16(pB[2] + kn, &lds[nxB + ldst[2]]);
            load_lds16(pB[3] + kn, &lds[nxB + ldst[3]]);
        }
        FENCE;
        __builtin_amdgcn_s_barrier();
        FENCE;
        MFMA16(4);
        FENCE;
        __builtin_amdgcn_s_barrier();
        FENCE;
    }
    __syncthreads();   // all staging reads done; no DMA in flight (last iter staged nothing)

    // ---- h2 tile (gelu(acc+b2), bf16) -> LDS overlay, XOR-swizzled [256][256] ----
#pragma unroll
    for (int i = 0; i < 8; ++i) {
        int row = wr + i * 16 + l15;
#pragma unroll
        for (int j = 0; j < 4; ++j) {
            int c = wc + j * 16 + q * 4;
            float4 b4 = *(const float4*)&b2v[c];
            float v0 = gelu_f(acc[i][j][0] + b4.x);
            float v1 = gelu_f(acc[i][j][1] + b4.y);
            float v2 = gelu_f(acc[i][j][2] + b4.z);
            float v3 = gelu_f(acc[i][j][3] + b4.w);
            uint2 pk;
            pk.x = (u32)f2b(v0) | ((u32)f2b(v1) << 16);
            pk.y = (u32)f2b(v2) | ((u32)f2b(v3) << 16);
            int gr = c >> 3;                                    // k-granule 0..31
            int addr = row * 256 + ((gr ^ (row & 7)) << 3) + (q & 1) * 4;
            *(uint2*)&lds[addr] = pk;
        }
    }
    __syncthreads();

    // ---- gemm3: h3 = h2 @ W3 + b3, A stationary in LDS, B from global (L2) ----
#pragma unroll
    for (int i = 0; i < 8; ++i)
#pragma unroll
        for (int j = 0; j < 4; ++j)
            acc[i][j] = (floatx4){0.f, 0.f, 0.f, 0.f};

    for (int ks = 0; ks < 8; ++ks) {             // K3 = 256
        int gidx = ks * 4 + q;
        short8 af[8], bg[4];
#pragma unroll
        for (int j = 0; j < 4; ++j) {
            int colr = wc + j * 16 + l15;
            bg[j] = *(const short8*)&W3T[(size_t)colr * 256 + gidx * 8];
        }
#pragma unroll
        for (int i = 0; i < 8; ++i) {
            int row = wr + i * 16 + l15;
            af[i] = *(const short8*)&lds[row * 256 + ((gidx ^ (row & 7)) << 3)];
        }
        __builtin_amdgcn_s_setprio(1);
#pragma unroll
        for (int i = 0; i < 8; ++i)
#pragma unroll
            for (int j = 0; j < 4; ++j)
                acc[i][j] = __builtin_amdgcn_mfma_f32_16x16x32_bf16(bg[j], af[i], acc[i][j], 0, 0, 0);
        __builtin_amdgcn_s_setprio(0);
    }
    __syncthreads();   // all h2 LDS reads done before overwrite

    // ---- h3 tile (bf16) -> LDS, XOR-swizzled by row&31 (conflict-light head reads) ----
#pragma unroll
    for (int i = 0; i < 8; ++i) {
        int row = wr + i * 16 + l15;
#pragma unroll
        for (int j = 0; j < 4; ++j) {
            int c = wc + j * 16 + q * 4;
            float4 b4 = *(const float4*)&b3v[c];
            float v0 = acc[i][j][0] + b4.x;
            float v1 = acc[i][j][1] + b4.y;
            float v2 = acc[i][j][2] + b4.z;
            float v3 = acc[i][j][3] + b4.w;
            uint2 pk;
            pk.x = (u32)f2b(v0) | ((u32)f2b(v1) << 16);
            pk.y = (u32)f2b(v2) | ((u32)f2b(v3) << 16);
            int gr = c >> 3;
            int addr = row * 256 + ((gr ^ (row & 31)) << 3) + (q & 1) * 4;
            *(uint2*)&lds[addr] = pk;
        }
    }
    __syncthreads();

    // ---- head: out = tanh(dyt_w*tanh(alpha*gelu(h3@Wo+bo))+dyt_b), scatter ----
    {
        int r = tid >> 1;                        // 2 threads per row
        int chalf = (tid & 1) * 4;               // channels [chalf, chalf+4)
        int n = row0 + r;
        int lo = 0, hi = NUM_GRAPHS;
        while (hi - lo > 1) {                    // largest g with soff[g] <= n
            int mid = (lo + hi) >> 1;
            if (soff[mid] <= n) lo = mid; else hi = mid;
        }
        int g = lo;
        int p = n - soff[g];
        float4 a4 = *(const float4*)&bo[chalf];
#pragma unroll 4
        for (int kk = 0; kk < 32; ++kk) {        // k = kk*8+e ascending (head_k order)
            short8 h = *(const short8*)&lds[r * 256 + ((kk ^ (r & 31)) << 3)];
#pragma unroll
            for (int e = 0; e < 8; ++e) {
                float hv = __uint_as_float((u32)(u16)h[e] << 16);
                const float* w = &sWo[(kk * 8 + e) * 8 + chalf];
                a4.x += hv * w[0];
                a4.y += hv * w[1];
                a4.z += hv * w[2];
                a4.w += hv * w[3];
            }
        }
        float alpha = alpha_p[0];
        float av[4] = {a4.x, a4.y, a4.z, a4.w};
        float rv[4];
#pragma unroll
        for (int c = 0; c < 4; ++c) {
            float a = gelu_f(av[c]);
            a = dyt_w[chalf + c] * tanh_f(alpha * a) + dyt_b[chalf + c];
            rv[c] = tanh_f(a);
        }
        *(float4*)&out[((size_t)(p * NUM_GRAPHS + g)) * 8 + chalf] =
            make_float4(rv[0], rv[1], rv[2], rv[3]);
    }
#undef LDA2
#undef LDB2
#undef MFMA16
}

extern "C" void kernel_launch(void* const* d_in, const int* in_sizes, int n_in,
                              void* d_out, int out_size, void* d_ws, size_t ws_size,
                              hipStream_t stream) {
    (void)in_sizes; (void)n_in; (void)out_size; (void)ws_size;
    const float* x_res = (const float*)d_in[0];
    const int*   batch = (const int*)d_in[1];
    const float* gamma = (const float*)d_in[2];
    const float* beta  = (const float*)d_in[3];
    const float* W1    = (const float*)d_in[4];
    const float* b1    = (const float*)d_in[5];
    const float* W2    = (const float*)d_in[6];
    const float* b2    = (const float*)d_in[7];
    const float* W3    = (const float*)d_in[8];
    const float* b3    = (const float*)d_in[9];
    const float* Wo    = (const float*)d_in[10];
    const float* bo    = (const float*)d_in[11];
    const float* alpha = (const float*)d_in[12];
    const float* dyt_w = (const float*)d_in[13];
    const float* dyt_b = (const float*)d_in[14];
    float* out = (float*)d_out;

    char* ws = (char*)d_ws;
    float* scale = (float*)(ws + 0);
    float* shift = (float*)(ws + 2048);
    float* b1f   = (float*)(ws + 4096);
    int*   offs  = (int*)(ws + 8192);
    u16* W1T = (u16*)(ws + 16384);                       // 512KB
    u16* W2T = (u16*)(ws + 16384 + 524288);              // 256KB
    u16* W3T = (u16*)(ws + 16384 + 524288 + 262144);     // 128KB
    const size_t MB = 1024 * 1024;
    u16* xb = (u16*)(ws + 2 * MB);              // 64MB  [2,66)
    u16* h1 = (u16*)(ws + 66 * MB);             // 64MB  [66,130)
    float4* partials = (float4*)(ws + 66 * MB); // 8MB   (aliases h1; dead before GEMM1)

    statscast_k<<<BN_BLOCKS, 256, 0, stream>>>(x_res, xb, partials);
    bn_reduce_k<<<256, 256, 0, stream>>>(partials, gamma, beta, scale, shift);
    prep_k<<<2306, 256, 0, stream>>>(W1, W2, W3, b1, scale, shift,
                                     W1T, W2T, W3T, b1f, batch, offs,
                                     bo, alpha, dyt_w, dyt_b, out);
    gemm_bt8_k<1, 2><<<512, 512, 0, stream>>>(xb, W1T, b1f, h1, 512, 512);
    gemm23h_k<<<256, 512, 0, stream>>>(h1, W2T, b2, W3T, b3, Wo, bo, offs,
                                       alpha, dyt_w, dyt_b, out);
}

// Round 5
// 361.023 us; speedup vs baseline: 1.0136x; 1.0136x over previous
//
#include <hip/hip_runtime.h>
#include <hip/hip_bf16.h>

#define N_NODES 65536
#define IN_CH 512
#define HIDDEN 256
#define OUT_CH 8
#define NUM_GRAPHS 32
#define MAX_LEN 4096
#define BN_EPS 1e-5f
#define BN_BLOCKS 2048

using short8  = __attribute__((ext_vector_type(8))) short;
using floatx4 = __attribute__((ext_vector_type(4))) float;
typedef unsigned int u32;
typedef unsigned short u16;

__device__ inline u16 f2b(float f) {
    u32 u = __float_as_uint(f);
    u += 0x7FFFu + ((u >> 16) & 1u);
    return (u16)(u >> 16);
}
// GELU tanh-form via hw exp+rcp; max abs err vs exact-erf ~3e-4.
__device__ inline float gelu_f(float x) {
    float z = x + 0.044715f * x * x * x;
    float e = __builtin_exp2f(-2.3022078f * z);
    return x * __builtin_amdgcn_rcpf(1.0f + e);
}
__device__ inline float tanh_f(float y) {
    y = fminf(fmaxf(y, -20.0f), 20.0f);
    float t = __builtin_exp2f(2.885390082f * y);
    return (t - 1.0f) * __builtin_amdgcn_rcpf(t + 1.0f);
}
__device__ inline void load_lds16(const void* g, void* l) {
    __builtin_amdgcn_global_load_lds(
        (const __attribute__((address_space(1))) u32*)g,
        (__attribute__((address_space(3))) u32*)l, 16, 0, 0);
}

// ---- statscast + stats-independent prep appendix ----
// bid <  2048 : per-channel sum/sumsq partials + raw bf16 cast of x
// bid [2048,2560): W2T transpose+cast          (stats-independent)
// bid [2560,2816): W3T transpose+cast          (stats-independent)
// bid [2816,3328): out pad-slot fill           (stats-independent)
// bid == 3328  : graph offsets binary search   (stats-independent)
__global__ __launch_bounds__(256) void statscast_k(const float* __restrict__ x,
                                                   u16* __restrict__ xb,
                                                   float4* __restrict__ partials,
                                                   const float* __restrict__ W2,
                                                   const float* __restrict__ W3,
                                                   u16* __restrict__ W2T,
                                                   u16* __restrict__ W3T,
                                                   const int* __restrict__ batch,
                                                   int* __restrict__ offsets,
                                                   const float* __restrict__ bo,
                                                   const float* __restrict__ alpha_p,
                                                   const float* __restrict__ dyt_w,
                                                   const float* __restrict__ dyt_b,
                                                   float* __restrict__ out) {
    __shared__ float4 sS[128];
    __shared__ float4 sQ[128];
    __shared__ int sof2[NUM_GRAPHS + 1];
    int tid = threadIdx.x;
    int bid = blockIdx.x;
    if (bid < 2048) {
        int half = tid >> 7;
        int c = tid & 127;
        const float4* x4 = (const float4*)x;
        uint2* xb2 = (uint2*)xb;
        float4 s = make_float4(0.f, 0.f, 0.f, 0.f);
        float4 q = make_float4(0.f, 0.f, 0.f, 0.f);
        int row0 = bid * 32;
#pragma unroll
        for (int r = half; r < 32; r += 2) {
            size_t off = (size_t)(row0 + r) * 128 + c;
            float4 v = x4[off];
            s.x += v.x; s.y += v.y; s.z += v.z; s.w += v.w;
            q.x += v.x * v.x; q.y += v.y * v.y; q.z += v.z * v.z; q.w += v.w * v.w;
            uint2 o;
            o.x = (u32)f2b(v.x) | ((u32)f2b(v.y) << 16);
            o.y = (u32)f2b(v.z) | ((u32)f2b(v.w) << 16);
            xb2[off] = o;
        }
        if (half == 1) { sS[c] = s; sQ[c] = q; }
        __syncthreads();
        if (half == 0) {
            float4 s2 = sS[c], q2 = sQ[c];
            s.x += s2.x; s.y += s2.y; s.z += s2.z; s.w += s2.w;
            q.x += q2.x; q.y += q2.y; q.z += q2.z; q.w += q2.w;
            partials[(size_t)bid * 256 + c * 2]     = make_float4(s.x, q.x, s.y, q.y);
            partials[(size_t)bid * 256 + c * 2 + 1] = make_float4(s.z, q.z, s.w, q.w);
        }
    } else if (bid < 2560) {                      // W2 [512,256] -> W2T [256,512]
        int i = (bid - 2048) * 256 + tid;
        int k = i >> 8, m = i & 255;
        W2T[(size_t)m * 512 + k] = f2b(W2[i]);
    } else if (bid < 2816) {                      // W3 [256,256] -> W3T [256,256]
        int i = (bid - 2560) * 256 + tid;
        int k = i >> 8, m = i & 255;
        W3T[(size_t)m * 256 + k] = f2b(W3[i]);
    } else if (bid < 3328) {                      // pad-slot fill of out
        if (tid < NUM_GRAPHS + 1) {
            int target = tid;
            int lo = 0, hi = N_NODES;
            while (lo < hi) {
                int mid = (lo + hi) >> 1;
                if (batch[mid] < target) lo = mid + 1; else hi = mid;
            }
            sof2[tid] = lo;
        }
        __syncthreads();
        int idx = (bid - 2816) * 256 + tid;       // 512 blocks -> 131072 slots
        int g = idx & 31;
        int p = idx >> 5;
        if (p >= sof2[g + 1] - sof2[g]) {
            float alpha = alpha_p[0];
            float rv[8];
#pragma unroll
            for (int c = 0; c < 8; ++c) {
                float a = gelu_f(bo[c]);
                a = dyt_w[c] * tanh_f(alpha * a) + dyt_b[c];
                rv[c] = tanh_f(a);
            }
            float4* o = (float4*)(out + (size_t)idx * OUT_CH);
            o[0] = make_float4(rv[0], rv[1], rv[2], rv[3]);
            o[1] = make_float4(rv[4], rv[5], rv[6], rv[7]);
        }
    } else {                                      // graph offsets
        if (tid < NUM_GRAPHS + 1) {
            int gph = tid;
            int lo = 0, hi = N_NODES;
            while (lo < hi) {
                int mid = (lo + hi) >> 1;
                if (batch[mid] < gph) lo = mid + 1; else hi = mid;
            }
            offsets[gph] = lo;
        }
    }
}

// ---- reduce partials -> scale/shift, then write this block's 2 W1T columns ----
// Block g owns channels c0=2g, c1=2g+1: computes their scale/shift AND the
// scale-folded W1T columns k=c0,c1 (same expression/order as old prep_k).
__global__ __launch_bounds__(256) void bn_reduce_k(const float4* __restrict__ partials,
                                                   const float* __restrict__ gamma,
                                                   const float* __restrict__ beta,
                                                   const float* __restrict__ W1,
                                                   float* __restrict__ scale,
                                                   float* __restrict__ shift,
                                                   u16* __restrict__ W1T) {
    __shared__ float4 sd[256];
    __shared__ float ssc[2];
    int tid = threadIdx.x;
    int g = blockIdx.x;
    float4 a = make_float4(0.f, 0.f, 0.f, 0.f);
    for (int r = tid; r < BN_BLOCKS; r += 256) {
        float4 v = partials[(size_t)r * 256 + g];
        a.x += v.x; a.y += v.y; a.z += v.z; a.w += v.w;
    }
    sd[tid] = a;
    __syncthreads();
    for (int st = 128; st > 0; st >>= 1) {
        if (tid < st) {
            float4 b = sd[tid + st];
            float4 m = sd[tid];
            m.x += b.x; m.y += b.y; m.z += b.z; m.w += b.w;
            sd[tid] = m;
        }
        __syncthreads();
    }
    int c0 = g * 2, c1 = g * 2 + 1;
    if (tid == 0) {
        float4 t = sd[0];
        const float inv = 1.0f / N_NODES;
        float mu0 = t.x * inv, var0 = t.y * inv - mu0 * mu0;
        float mu1 = t.z * inv, var1 = t.w * inv - mu1 * mu1;
        float sc0 = gamma[c0] * rsqrtf(var0 + BN_EPS);
        float sc1 = gamma[c1] * rsqrtf(var1 + BN_EPS);
        scale[c0] = sc0; shift[c0] = beta[c0] - mu0 * sc0;
        scale[c1] = sc1; shift[c1] = beta[c1] - mu1 * sc1;
        ssc[0] = sc0; ssc[1] = sc1;
    }
    __syncthreads();
    float s0 = ssc[0], s1 = ssc[1];
#pragma unroll
    for (int mm = tid; mm < 512; mm += 256) {
        W1T[(size_t)mm * 512 + c0] = f2b(s0 * W1[(size_t)c0 * 512 + mm]);
        W1T[(size_t)mm * 512 + c1] = f2b(s1 * W1[(size_t)c1 * 512 + mm]);
    }
}

// ---- b1f fold (bias with BN shift folded through W1) -- exact prep_k order ----
__global__ __launch_bounds__(256) void b1f_k(const float* __restrict__ W1,
                                             const float* __restrict__ b1,
                                             const float* __restrict__ shift,
                                             float* __restrict__ b1f) {
    int m = blockIdx.x * 256 + threadIdx.x;
    float acc = b1[m];
#pragma unroll 16
    for (int k = 0; k < 512; ++k) acc += shift[k] * W1[k * 512 + m];
    b1f[m] = acc;
}

// ---------------- GEMM1: C[N,M] = gelu(A[N,K] @ BT[M,K]^T + bias) ----------------
// 256x128 block tile, 512 threads (8 waves, 4x2), BK=64, 4x4 MFMA per wave.
// 2-phase, 48KB LDS (2-3 blocks/CU: cross-block overlap covers the drain).
// Measured-best for standalone gemm (r4 A/B: 8-phase/1blk-CU is +13us worse).
template <int DO_GELU, int NXB>
__global__ __launch_bounds__(512) void gemm_bt_k(const u16* __restrict__ A,
                                                 const u16* __restrict__ BT,
                                                 const float* __restrict__ bias,
                                                 u16* __restrict__ C,
                                                 int K, int M) {
    __shared__ __align__(16) u16 As[256 * 64];   // 32KB
    __shared__ __align__(16) u16 Bs[128 * 64];   // 16KB
    int tid = threadIdx.x;
    int lane = tid & 63;
    int bid = blockIdx.x;
    int xcd = bid & 7;
    int slot = bid >> 3;
    int rloc = slot / NXB;
    int colb = slot - rloc * NXB;
    int row0 = (xcd * 32 + rloc) * 256;
    int col0 = colb * 128;
    int wave = tid >> 6;
    int wr = (wave >> 1) * 64;     // 0..192
    int wc = (wave & 1) * 64;      // 0/64
    int l15 = lane & 15;
    int q = lane >> 4;

    floatx4 acc[4][4] = {};

    const int nkt = K >> 6;
    for (int kt = 0; kt < nkt; ++kt) {
        int k0 = kt << 6;
#pragma unroll
        for (int s = 0; s < 4; ++s) {            // A: 256x64 = 2048 chunks
            int li = s * 512 + tid;
            int r = li >> 3;
            int g = li & 7;
            int gs = g ^ (r & 7);
            load_lds16(&A[(size_t)(row0 + r) * K + k0 + gs * 8], &As[li * 8]);
        }
#pragma unroll
        for (int s = 0; s < 2; ++s) {            // B: 128x64 = 1024 chunks
            int li = s * 512 + tid;
            int r = li >> 3;
            int g = li & 7;
            int gs = g ^ (r & 7);
            load_lds16(&BT[(size_t)(col0 + r) * K + k0 + gs * 8], &Bs[li * 8]);
        }
        __syncthreads();
#pragma unroll
        for (int ks = 0; ks < 2; ++ks) {
            int gidx = ks * 4 + q;
            short8 af[4], bg[4];
#pragma unroll
            for (int i = 0; i < 4; ++i) {
                int row = wr + i * 16 + l15;
                af[i] = *(const short8*)&As[row * 64 + (gidx ^ (row & 7)) * 8];
            }
#pragma unroll
            for (int j = 0; j < 4; ++j) {
                int row = wc + j * 16 + l15;
                bg[j] = *(const short8*)&Bs[row * 64 + (gidx ^ (row & 7)) * 8];
            }
#pragma unroll
            for (int i = 0; i < 4; ++i)
#pragma unroll
                for (int j = 0; j < 4; ++j)
                    acc[i][j] = __builtin_amdgcn_mfma_f32_16x16x32_bf16(bg[j], af[i], acc[i][j], 0, 0, 0);
        }
        __syncthreads();
    }
    // epilogue (swapped D): row = row0+wr+i*16+l15 ; col = col0+wc+j*16+q*4+reg
#pragma unroll
    for (int i = 0; i < 4; ++i) {
        size_t rbase = (size_t)(row0 + wr + i * 16 + l15) * M;
#pragma unroll
        for (int j = 0; j < 4; ++j) {
            int c = col0 + wc + j * 16 + q * 4;
            float4 b4 = *(const float4*)&bias[c];
            float v0 = acc[i][j][0] + b4.x;
            float v1 = acc[i][j][1] + b4.y;
            float v2 = acc[i][j][2] + b4.z;
            float v3 = acc[i][j][3] + b4.w;
            if (DO_GELU) { v0 = gelu_f(v0); v1 = gelu_f(v1); v2 = gelu_f(v2); v3 = gelu_f(v3); }
            uint2 pk;
            pk.x = (u32)f2b(v0) | ((u32)f2b(v1) << 16);
            pk.y = (u32)f2b(v2) | ((u32)f2b(v3) << 16);
            *(uint2*)&C[rbase + c] = pk;
        }
    }
}

// -------- fused GEMM2+GEMM3+HEAD: out = head(gelu(h1@W2+b2)@W3 + b3) --------
// Block owns 256 rows end-to-end. gemm2: 8-phase counted-vmcnt dbuf pipeline
// (128KB LDS -- the one place 8-phase wins, since 1 blk/CU means no
// cross-block overlap). h2 tile overlays the staging dbuf. gemm3: A stationary
// in LDS, B = W3T from global (L2). h3 tile stays in LDS (never HBM). head:
// 2 threads/row x 4 channels, k ascending (bit-identical to old head_k).
#define FENCE asm volatile("" ::: "memory")

__global__ __launch_bounds__(512, 2) void gemm23h_k(const u16* __restrict__ A,
                                                    const u16* __restrict__ B2T,
                                                    const float* __restrict__ b2v,
                                                    const u16* __restrict__ W3T,
                                                    const float* __restrict__ b3v,
                                                    const float* __restrict__ Wo,
                                                    const float* __restrict__ bo,
                                                    const int* __restrict__ offsets,
                                                    const float* __restrict__ alpha_p,
                                                    const float* __restrict__ dyt_w,
                                                    const float* __restrict__ dyt_b,
                                                    float* __restrict__ out) {
    __shared__ __align__(16) u16 lds[65536];   // 128KB: staging dbuf -> h2 tile -> h3 tile
    __shared__ float sWo[HIDDEN * OUT_CH];     // 8KB
    __shared__ int soff[NUM_GRAPHS + 1];
    int tid = threadIdx.x;
    int lane = tid & 63;
    int bid = blockIdx.x;
    int xcd = bid & 7;
    int slot = bid >> 3;
    int row0 = (xcd * 32 + slot) * 256;
    int wave = tid >> 6;
    int wr = (wave >> 2) * 128;    // 0/128
    int wc = (wave & 3) * 64;      // 0..192
    int l15 = lane & 15;
    int q = lane >> 4;

    // stage Wo + graph offsets early (consumed only in the head phase)
    ((float4*)sWo)[tid] = ((const float4*)Wo)[tid];
    if (tid < NUM_GRAPHS + 1) soff[tid] = offsets[tid];

    floatx4 acc[8][4] = {};

    const u16* pA[4];
    const u16* pB[4];
    int ldst[4];
#pragma unroll
    for (int s = 0; s < 4; ++s) {
        int li = s * 512 + tid;
        int r = li >> 3;
        int g = li & 7;
        int gs = g ^ (r & 7);                    // pre-swizzled global source
        pA[s] = A + (size_t)(row0 + r) * 512 + gs * 8;
        pB[s] = B2T + (size_t)r * 512 + gs * 8;
        ldst[s] = li * 8;                        // linear LDS dest (u16 units)
    }

#define LDA2(BASE, GIDX)                                                             \
    _Pragma("unroll")                                                                \
    for (int i = 0; i < 4; ++i) {                                                    \
        int row = (BASE) + i * 16 + l15;                                             \
        af[i] = *(const short8*)&lds[curA + row * 64 + (((GIDX) ^ (row & 7)) << 3)]; \
    }
#define LDB2(BASE, GIDX)                                                             \
    _Pragma("unroll")                                                                \
    for (int j = 0; j < 4; ++j) {                                                    \
        int row = (BASE) + j * 16 + l15;                                             \
        bg[j] = *(const short8*)&lds[curB + row * 64 + (((GIDX) ^ (row & 7)) << 3)]; \
    }
#define MFMA16(IB)                                                                   \
    __builtin_amdgcn_s_setprio(1);                                                   \
    _Pragma("unroll")                                                                \
    for (int i = 0; i < 4; ++i)                                                      \
        _Pragma("unroll")                                                            \
        for (int j = 0; j < 4; ++j)                                                  \
            acc[(IB) + i][j] = __builtin_amdgcn_mfma_f32_16x16x32_bf16(              \
                bg[j], af[i], acc[(IB) + i][j], 0, 0, 0);                            \
    __builtin_amdgcn_s_setprio(0)

    // prologue: stage tile 0 into buf 0 (8 loads in flight)
#pragma unroll
    for (int s = 0; s < 4; ++s) load_lds16(pA[s], &lds[ldst[s]]);
#pragma unroll
    for (int s = 0; s < 4; ++s) load_lds16(pB[s], &lds[32768 + ldst[s]]);

    const int nt = 8;                            // K2 = 512
    for (int t = 0; t < nt; ++t) {
        const int cur = t & 1;
        const int nx = cur ^ 1;
        const bool last = (t + 1 == nt);
        const int kn = (t + 1) << 6;
        const int curA = cur * 16384, curB = 32768 + cur * 16384;
        const int nxA = nx * 16384,  nxB = 32768 + nx * 16384;
        short8 af[4], bg[4];

        // ---- phase 0: ks=0, rows 0..63 of wave tile ----
        if (!last) {
            load_lds16(pA[0] + kn, &lds[nxA + ldst[0]]);
            load_lds16(pA[1] + kn, &lds[nxA + ldst[1]]);
        }
        if (last) asm volatile("s_waitcnt vmcnt(0)" ::: "memory");  // tile-7: drain all
        else      asm volatile("s_waitcnt vmcnt(2)" ::: "memory");  // tile-t landed, 2 in flight
        __builtin_amdgcn_s_barrier();
        FENCE;
        LDA2(wr, q);
        LDB2(wc, q);
        MFMA16(0);
        FENCE;
        __builtin_amdgcn_s_barrier();
        // ---- phase 1: ks=0, rows 64..127 ----
        LDA2(wr + 64, q);
        if (!last) {
            load_lds16(pA[2] + kn, &lds[nxA + ldst[2]]);
            load_lds16(pA[3] + kn, &lds[nxA + ldst[3]]);
        }
        FENCE;
        __builtin_amdgcn_s_barrier();
        FENCE;
        MFMA16(4);
        FENCE;
        __builtin_amdgcn_s_barrier();
        // ---- phase 2: ks=1, rows 0..63 ----
        LDA2(wr, 4 + q);
        LDB2(wc, 4 + q);
        if (!last) {
            load_lds16(pB[0] + kn, &lds[nxB + ldst[0]]);
            load_lds16(pB[1] + kn, &lds[nxB + ldst[1]]);
        }
        FENCE;
        __builtin_amdgcn_s_barrier();
        FENCE;
        MFMA16(0);
        FENCE;
        __builtin_amdgcn_s_barrier();
        // ---- phase 3: ks=1, rows 64..127 ----
        LDA2(wr + 64, 4 + q);
        if (!last) {
            load_lds16(pB[2] + kn, &lds[nxB + ldst[2]]);
            load_lds16(pB[3] + kn, &lds[nxB + ldst[3]]);
        }
        FENCE;
        __builtin_amdgcn_s_barrier();
        FENCE;
        MFMA16(4);
        FENCE;
        __builtin_amdgcn_s_barrier();
        FENCE;
    }
    __syncthreads();   // all staging reads done; no DMA in flight (last iter staged nothing)

    // ---- h2 tile (gelu(acc+b2), bf16) -> LDS overlay, XOR-swizzled [256][256] ----
#pragma unroll
    for (int i = 0; i < 8; ++i) {
        int row = wr + i * 16 + l15;
#pragma unroll
        for (int j = 0; j < 4; ++j) {
            int c = wc + j * 16 + q * 4;
            float4 b4 = *(const float4*)&b2v[c];
            float v0 = gelu_f(acc[i][j][0] + b4.x);
            float v1 = gelu_f(acc[i][j][1] + b4.y);
            float v2 = gelu_f(acc[i][j][2] + b4.z);
            float v3 = gelu_f(acc[i][j][3] + b4.w);
            uint2 pk;
            pk.x = (u32)f2b(v0) | ((u32)f2b(v1) << 16);
            pk.y = (u32)f2b(v2) | ((u32)f2b(v3) << 16);
            int gr = c >> 3;                                    // k-granule 0..31
            int addr = row * 256 + ((gr ^ (row & 7)) << 3) + (q & 1) * 4;
            *(uint2*)&lds[addr] = pk;
        }
    }
    __syncthreads();

    // ---- gemm3: h3 = h2 @ W3 + b3, A stationary in LDS, B from global (L2) ----
#pragma unroll
    for (int i = 0; i < 8; ++i)
#pragma unroll
        for (int j = 0; j < 4; ++j)
            acc[i][j] = (floatx4){0.f, 0.f, 0.f, 0.f};

    for (int ks = 0; ks < 8; ++ks) {             // K3 = 256
        int gidx = ks * 4 + q;
        short8 af[8], bg[4];
#pragma unroll
        for (int j = 0; j < 4; ++j) {
            int colr = wc + j * 16 + l15;
            bg[j] = *(const short8*)&W3T[(size_t)colr * 256 + gidx * 8];
        }
#pragma unroll
        for (int i = 0; i < 8; ++i) {
            int row = wr + i * 16 + l15;
            af[i] = *(const short8*)&lds[row * 256 + ((gidx ^ (row & 7)) << 3)];
        }
        __builtin_amdgcn_s_setprio(1);
#pragma unroll
        for (int i = 0; i < 8; ++i)
#pragma unroll
            for (int j = 0; j < 4; ++j)
                acc[i][j] = __builtin_amdgcn_mfma_f32_16x16x32_bf16(bg[j], af[i], acc[i][j], 0, 0, 0);
        __builtin_amdgcn_s_setprio(0);
    }
    __syncthreads();   // all h2 LDS reads done before overwrite

    // ---- h3 tile (bf16) -> LDS, XOR-swizzled by row&31 (conflict-light head reads) ----
#pragma unroll
    for (int i = 0; i < 8; ++i) {
        int row = wr + i * 16 + l15;
#pragma unroll
        for (int j = 0; j < 4; ++j) {
            int c = wc + j * 16 + q * 4;
            float4 b4 = *(const float4*)&b3v[c];
            float v0 = acc[i][j][0] + b4.x;
            float v1 = acc[i][j][1] + b4.y;
            float v2 = acc[i][j][2] + b4.z;
            float v3 = acc[i][j][3] + b4.w;
            uint2 pk;
            pk.x = (u32)f2b(v0) | ((u32)f2b(v1) << 16);
            pk.y = (u32)f2b(v2) | ((u32)f2b(v3) << 16);
            int gr = c >> 3;
            int addr = row * 256 + ((gr ^ (row & 31)) << 3) + (q & 1) * 4;
            *(uint2*)&lds[addr] = pk;
        }
    }
    __syncthreads();

    // ---- head: out = tanh(dyt_w*tanh(alpha*gelu(h3@Wo+bo))+dyt_b), scatter ----
    {
        int r = tid >> 1;                        // 2 threads per row
        int chalf = (tid & 1) * 4;               // channels [chalf, chalf+4)
        int n = row0 + r;
        int lo = 0, hi = NUM_GRAPHS;
        while (hi - lo > 1) {                    // largest g with soff[g] <= n
            int mid = (lo + hi) >> 1;
            if (soff[mid] <= n) lo = mid; else hi = mid;
        }
        int g = lo;
        int p = n - soff[g];
        float4 a4 = *(const float4*)&bo[chalf];
#pragma unroll 4
        for (int kk = 0; kk < 32; ++kk) {        // k = kk*8+e ascending (head_k order)
            short8 h = *(const short8*)&lds[r * 256 + ((kk ^ (r & 31)) << 3)];
#pragma unroll
            for (int e = 0; e < 8; ++e) {
                float hv = __uint_as_float((u32)(u16)h[e] << 16);
                const float* w = &sWo[(kk * 8 + e) * 8 + chalf];
                a4.x += hv * w[0];
                a4.y += hv * w[1];
                a4.z += hv * w[2];
                a4.w += hv * w[3];
            }
        }
        float alpha = alpha_p[0];
        float av[4] = {a4.x, a4.y, a4.z, a4.w};
        float rv[4];
#pragma unroll
        for (int c = 0; c < 4; ++c) {
            float a = gelu_f(av[c]);
            a = dyt_w[chalf + c] * tanh_f(alpha * a) + dyt_b[chalf + c];
            rv[c] = tanh_f(a);
        }
        *(float4*)&out[((size_t)(p * NUM_GRAPHS + g)) * 8 + chalf] =
            make_float4(rv[0], rv[1], rv[2], rv[3]);
    }
#undef LDA2
#undef LDB2
#undef MFMA16
}

extern "C" void kernel_launch(void* const* d_in, const int* in_sizes, int n_in,
                              void* d_out, int out_size, void* d_ws, size_t ws_size,
                              hipStream_t stream) {
    (void)in_sizes; (void)n_in; (void)out_size; (void)ws_size;
    const float* x_res = (const float*)d_in[0];
    const int*   batch = (const int*)d_in[1];
    const float* gamma = (const float*)d_in[2];
    const float* beta  = (const float*)d_in[3];
    const float* W1    = (const float*)d_in[4];
    const float* b1    = (const float*)d_in[5];
    const float* W2    = (const float*)d_in[6];
    const float* b2    = (const float*)d_in[7];
    const float* W3    = (const float*)d_in[8];
    const float* b3    = (const float*)d_in[9];
    const float* Wo    = (const float*)d_in[10];
    const float* bo    = (const float*)d_in[11];
    const float* alpha = (const float*)d_in[12];
    const float* dyt_w = (const float*)d_in[13];
    const float* dyt_b = (const float*)d_in[14];
    float* out = (float*)d_out;

    char* ws = (char*)d_ws;
    float* scale = (float*)(ws + 0);
    float* shift = (float*)(ws + 2048);
    float* b1f   = (float*)(ws + 4096);
    int*   offs  = (int*)(ws + 8192);
    u16* W1T = (u16*)(ws + 16384);                       // 512KB
    u16* W2T = (u16*)(ws + 16384 + 524288);              // 256KB
    u16* W3T = (u16*)(ws + 16384 + 524288 + 262144);     // 128KB
    const size_t MB = 1024 * 1024;
    u16* xb = (u16*)(ws + 2 * MB);              // 64MB  [2,66)
    u16* h1 = (u16*)(ws + 66 * MB);             // 64MB  [66,130)
    float4* partials = (float4*)(ws + 66 * MB); // 8MB   (aliases h1; dead before GEMM1)

    statscast_k<<<3329, 256, 0, stream>>>(x_res, xb, partials, W2, W3, W2T, W3T,
                                          batch, offs, bo, alpha, dyt_w, dyt_b, out);
    bn_reduce_k<<<256, 256, 0, stream>>>(partials, gamma, beta, W1, scale, shift, W1T);
    b1f_k<<<2, 256, 0, stream>>>(W1, b1, shift, b1f);
    gemm_bt_k<1, 4><<<1024, 512, 0, stream>>>(xb, W1T, b1f, h1, 512, 512);
    gemm23h_k<<<256, 512, 0, stream>>>(h1, W2T, b2, W3T, b3, Wo, bo, offs,
                                       alpha, dyt_w, dyt_b, out);
}

// Round 6
// 348.572 us; speedup vs baseline: 1.0499x; 1.0357x over previous
//
#include <hip/hip_runtime.h>
#include <hip/hip_bf16.h>

#define N_NODES 65536
#define IN_CH 512
#define HIDDEN 256
#define OUT_CH 8
#define NUM_GRAPHS 32
#define MAX_LEN 4096
#define BN_EPS 1e-5f
#define BN_BLOCKS 2048

using short8  = __attribute__((ext_vector_type(8))) short;
using floatx4 = __attribute__((ext_vector_type(4))) float;
typedef unsigned int u32;
typedef unsigned short u16;

__device__ inline u16 f2b(float f) {
    u32 u = __float_as_uint(f);
    u += 0x7FFFu + ((u >> 16) & 1u);
    return (u16)(u >> 16);
}
// GELU tanh-form via hw exp+rcp; max abs err vs exact-erf ~3e-4.
__device__ inline float gelu_f(float x) {
    float z = x + 0.044715f * x * x * x;
    float e = __builtin_exp2f(-2.3022078f * z);
    return x * __builtin_amdgcn_rcpf(1.0f + e);
}
__device__ inline float tanh_f(float y) {
    y = fminf(fmaxf(y, -20.0f), 20.0f);
    float t = __builtin_exp2f(2.885390082f * y);
    return (t - 1.0f) * __builtin_amdgcn_rcpf(t + 1.0f);
}
__device__ inline void load_lds16(const void* g, void* l) {
    __builtin_amdgcn_global_load_lds(
        (const __attribute__((address_space(1))) u32*)g,
        (__attribute__((address_space(3))) u32*)l, 16, 0, 0);
}

// ---- fused: per-channel sum/sumsq partials + raw bf16 cast of x ----
__global__ __launch_bounds__(256) void statscast_k(const float* __restrict__ x,
                                                   u16* __restrict__ xb,
                                                   float4* __restrict__ partials) {
    __shared__ float4 sS[128];
    __shared__ float4 sQ[128];
    int tid = threadIdx.x;
    int half = tid >> 7;
    int c = tid & 127;
    const float4* x4 = (const float4*)x;
    uint2* xb2 = (uint2*)xb;
    float4 s = make_float4(0.f, 0.f, 0.f, 0.f);
    float4 q = make_float4(0.f, 0.f, 0.f, 0.f);
    int row0 = blockIdx.x * 32;
#pragma unroll
    for (int r = half; r < 32; r += 2) {
        size_t off = (size_t)(row0 + r) * 128 + c;
        float4 v = x4[off];
        s.x += v.x; s.y += v.y; s.z += v.z; s.w += v.w;
        q.x += v.x * v.x; q.y += v.y * v.y; q.z += v.z * v.z; q.w += v.w * v.w;
        uint2 o;
        o.x = (u32)f2b(v.x) | ((u32)f2b(v.y) << 16);
        o.y = (u32)f2b(v.z) | ((u32)f2b(v.w) << 16);
        xb2[off] = o;
    }
    if (half == 1) { sS[c] = s; sQ[c] = q; }
    __syncthreads();
    if (half == 0) {
        float4 s2 = sS[c], q2 = sQ[c];
        s.x += s2.x; s.y += s2.y; s.z += s2.z; s.w += s2.w;
        q.x += q2.x; q.y += q2.y; q.z += q2.z; q.w += q2.w;
        partials[(size_t)blockIdx.x * 256 + c * 2]     = make_float4(s.x, q.x, s.y, q.y);
        partials[(size_t)blockIdx.x * 256 + c * 2 + 1] = make_float4(s.z, q.z, s.w, q.w);
    }
}

// ---- reduce partials -> scale/shift ----
__global__ __launch_bounds__(256) void bn_reduce_k(const float4* __restrict__ partials,
                                                   const float* __restrict__ gamma,
                                                   const float* __restrict__ beta,
                                                   float* __restrict__ scale,
                                                   float* __restrict__ shift) {
    __shared__ float4 sd[256];
    int tid = threadIdx.x;
    int g = blockIdx.x;
    float4 a = make_float4(0.f, 0.f, 0.f, 0.f);
    for (int r = tid; r < BN_BLOCKS; r += 256) {
        float4 v = partials[(size_t)r * 256 + g];
        a.x += v.x; a.y += v.y; a.z += v.z; a.w += v.w;
    }
    sd[tid] = a;
    __syncthreads();
    for (int st = 128; st > 0; st >>= 1) {
        if (tid < st) {
            float4 b = sd[tid + st];
            float4 m = sd[tid];
            m.x += b.x; m.y += b.y; m.z += b.z; m.w += b.w;
            sd[tid] = m;
        }
        __syncthreads();
    }
    if (tid == 0) {
        float4 t = sd[0];
        int c0 = g * 2, c1 = g * 2 + 1;
        const float inv = 1.0f / N_NODES;
        float mu0 = t.x * inv, var0 = t.y * inv - mu0 * mu0;
        float mu1 = t.z * inv, var1 = t.w * inv - mu1 * mu1;
        float sc0 = gamma[c0] * rsqrtf(var0 + BN_EPS);
        float sc1 = gamma[c1] * rsqrtf(var1 + BN_EPS);
        scale[c0] = sc0; shift[c0] = beta[c0] - mu0 * sc0;
        scale[c1] = sc1; shift[c1] = beta[c1] - mu1 * sc1;
    }
}

// ---- prep: W transposes/casts + folded bias b1f + graph offsets + pad-fill ----
__global__ __launch_bounds__(256) void prep_k(const float* __restrict__ W1,
                                              const float* __restrict__ W2,
                                              const float* __restrict__ W3,
                                              const float* __restrict__ b1,
                                              const float* __restrict__ scale,
                                              const float* __restrict__ shift,
                                              u16* __restrict__ W1T,
                                              u16* __restrict__ W2T,
                                              u16* __restrict__ W3T,
                                              float* __restrict__ b1f,
                                              const int* __restrict__ batch,
                                              int* __restrict__ offsets,
                                              const float* __restrict__ bo,
                                              const float* __restrict__ alpha_p,
                                              const float* __restrict__ dyt_w,
                                              const float* __restrict__ dyt_b,
                                              float* __restrict__ out) {
    __shared__ int sof2[NUM_GRAPHS + 1];
    int bid = blockIdx.x;
    int tid = threadIdx.x;
    if (bid < 1792) {
        int idx = bid * 256 + tid;
        if (idx < 262144) {                       // W1 [512,512]
            int k = idx >> 9, m = idx & 511;
            W1T[(size_t)m * 512 + k] = f2b(scale[k] * W1[idx]);
        } else if (idx < 262144 + 131072) {       // W2 [512,256]
            int i = idx - 262144;
            int k = i >> 8, m = i & 255;
            W2T[(size_t)m * 512 + k] = f2b(W2[i]);
        } else {                                  // W3 [256,256]
            int i = idx - 393216;
            int k = i >> 8, m = i & 255;
            W3T[(size_t)m * 256 + k] = f2b(W3[i]);
        }
        if (bid == 0 && tid < NUM_GRAPHS + 1) {
            int gph = tid;
            int lo = 0, hi = N_NODES;
            while (lo < hi) {
                int mid = (lo + hi) >> 1;
                if (batch[mid] < gph) lo = mid + 1; else hi = mid;
            }
            offsets[gph] = lo;
        }
    } else if (bid < 1794) {
        int m = (bid - 1792) * 256 + tid;
        float acc = b1[m];
#pragma unroll 16
        for (int k = 0; k < 512; ++k) acc += shift[k] * W1[k * 512 + m];
        b1f[m] = acc;
    } else {
        // pad-slot fill: each block recomputes graph boundaries (no dependence
        // on offsets[] written by bid 0 of this same kernel)
        if (tid < NUM_GRAPHS + 1) {
            int target = tid;
            int lo = 0, hi = N_NODES;
            while (lo < hi) {
                int mid = (lo + hi) >> 1;
                if (batch[mid] < target) lo = mid + 1; else hi = mid;
            }
            sof2[tid] = lo;
        }
        __syncthreads();
        int idx = (bid - 1794) * 256 + tid;       // 512 blocks -> 131072 slots
        int g = idx & 31;
        int p = idx >> 5;
        if (p >= sof2[g + 1] - sof2[g]) {
            float alpha = alpha_p[0];
            float rv[8];
#pragma unroll
            for (int c = 0; c < 8; ++c) {
                float a = gelu_f(bo[c]);
                a = dyt_w[c] * tanh_f(alpha * a) + dyt_b[c];
                rv[c] = tanh_f(a);
            }
            float4* o = (float4*)(out + (size_t)idx * OUT_CH);
            o[0] = make_float4(rv[0], rv[1], rv[2], rv[3]);
            o[1] = make_float4(rv[4], rv[5], rv[6], rv[7]);
        }
    }
}

// ---------------- GEMM1: C[N,M] = gelu(A[N,K] @ BT[M,K]^T + bias) ----------------
// 256x128 block tile, 512 threads (8 waves, 4x2), BK=64, 4x4 MFMA per wave.
// 2-phase, 48KB LDS (2-3 blocks/CU: cross-block overlap covers the drain).
template <int DO_GELU, int NXB>
__global__ __launch_bounds__(512) void gemm_bt_k(const u16* __restrict__ A,
                                                 const u16* __restrict__ BT,
                                                 const float* __restrict__ bias,
                                                 u16* __restrict__ C,
                                                 int K, int M) {
    __shared__ __align__(16) u16 As[256 * 64];   // 32KB
    __shared__ __align__(16) u16 Bs[128 * 64];   // 16KB
    int tid = threadIdx.x;
    int lane = tid & 63;
    int bid = blockIdx.x;
    int xcd = bid & 7;
    int slot = bid >> 3;
    int rloc = slot / NXB;
    int colb = slot - rloc * NXB;
    int row0 = (xcd * 32 + rloc) * 256;
    int col0 = colb * 128;
    int wave = tid >> 6;
    int wr = (wave >> 1) * 64;     // 0..192
    int wc = (wave & 1) * 64;      // 0/64
    int l15 = lane & 15;
    int q = lane >> 4;

    floatx4 acc[4][4] = {};

    const int nkt = K >> 6;
    for (int kt = 0; kt < nkt; ++kt) {
        int k0 = kt << 6;
#pragma unroll
        for (int s = 0; s < 4; ++s) {            // A: 256x64 = 2048 chunks
            int li = s * 512 + tid;
            int r = li >> 3;
            int g = li & 7;
            int gs = g ^ (r & 7);
            load_lds16(&A[(size_t)(row0 + r) * K + k0 + gs * 8], &As[li * 8]);
        }
#pragma unroll
        for (int s = 0; s < 2; ++s) {            // B: 128x64 = 1024 chunks
            int li = s * 512 + tid;
            int r = li >> 3;
            int g = li & 7;
            int gs = g ^ (r & 7);
            load_lds16(&BT[(size_t)(col0 + r) * K + k0 + gs * 8], &Bs[li * 8]);
        }
        __syncthreads();
#pragma unroll
        for (int ks = 0; ks < 2; ++ks) {
            int gidx = ks * 4 + q;
            short8 af[4], bg[4];
#pragma unroll
            for (int i = 0; i < 4; ++i) {
                int row = wr + i * 16 + l15;
                af[i] = *(const short8*)&As[row * 64 + (gidx ^ (row & 7)) * 8];
            }
#pragma unroll
            for (int j = 0; j < 4; ++j) {
                int row = wc + j * 16 + l15;
                bg[j] = *(const short8*)&Bs[row * 64 + (gidx ^ (row & 7)) * 8];
            }
#pragma unroll
            for (int i = 0; i < 4; ++i)
#pragma unroll
                for (int j = 0; j < 4; ++j)
                    acc[i][j] = __builtin_amdgcn_mfma_f32_16x16x32_bf16(bg[j], af[i], acc[i][j], 0, 0, 0);
        }
        __syncthreads();
    }
    // epilogue (swapped D): row = row0+wr+i*16+l15 ; col = col0+wc+j*16+q*4+reg
#pragma unroll
    for (int i = 0; i < 4; ++i) {
        size_t rbase = (size_t)(row0 + wr + i * 16 + l15) * M;
#pragma unroll
        for (int j = 0; j < 4; ++j) {
            int c = col0 + wc + j * 16 + q * 4;
            float4 b4 = *(const float4*)&bias[c];
            float v0 = acc[i][j][0] + b4.x;
            float v1 = acc[i][j][1] + b4.y;
            float v2 = acc[i][j][2] + b4.z;
            float v3 = acc[i][j][3] + b4.w;
            if (DO_GELU) { v0 = gelu_f(v0); v1 = gelu_f(v1); v2 = gelu_f(v2); v3 = gelu_f(v3); }
            uint2 pk;
            pk.x = (u32)f2b(v0) | ((u32)f2b(v1) << 16);
            pk.y = (u32)f2b(v2) | ((u32)f2b(v3) << 16);
            *(uint2*)&C[rbase + c] = pk;
        }
    }
}

// -------- fused GEMM2+GEMM3+HEAD: out = head(gelu(h1@W2+b2)@W3 + b3) --------
// r6 restructure: 128-row blocks, 512 blocks -> 2 blocks/CU (16 waves/CU) so
// cross-block overlap covers all phase barriers (r4/r5 lesson: 1 blk/CU + 8
// waves = MfmaUtil 11%). gemm2 = proven 2-phase structure (As 128x64 +
// Bs 256x64 = 48KB single-buffered staging). h2 tile [128][256] (64KB)
// overlays staging; gemm3 A-stationary in LDS, B=W3T from L2; h3 in LDS;
// head 4 threads/row x 2 channels. Per-element accumulation orders are
// identical to r3's kernel -> bit-identical out.
__global__ __launch_bounds__(512, 4) void gemm23h_k(const u16* __restrict__ A,
                                                    const u16* __restrict__ B2T,
                                                    const float* __restrict__ b2v,
                                                    const u16* __restrict__ W3T,
                                                    const float* __restrict__ b3v,
                                                    const float* __restrict__ Wo,
                                                    const float* __restrict__ bo,
                                                    const int* __restrict__ offsets,
                                                    const float* __restrict__ alpha_p,
                                                    const float* __restrict__ dyt_w,
                                                    const float* __restrict__ dyt_b,
                                                    float* __restrict__ out) {
    __shared__ __align__(16) u16 lds[32768];   // 64KB: staging (48KB) -> h2 tile -> h3 tile
    __shared__ float sWo[HIDDEN * OUT_CH];     // 8KB
    __shared__ int soff[NUM_GRAPHS + 1];
    int tid = threadIdx.x;
    int lane = tid & 63;
    int bid = blockIdx.x;
    int xcd = bid & 7;
    int slot = bid >> 3;                       // 0..63
    int row0 = (xcd * 64 + slot) * 128;
    int wave = tid >> 6;
    int wr = (wave >> 2) * 64;     // 0/64
    int wc = (wave & 3) * 64;      // 0..192
    int l15 = lane & 15;
    int q = lane >> 4;

    // stage Wo + graph offsets early (consumed only in the head phase)
    ((float4*)sWo)[tid] = ((const float4*)Wo)[tid];
    if (tid < NUM_GRAPHS + 1) soff[tid] = offsets[tid];

    floatx4 acc[4][4] = {};

    // staging: A 128x64 = 1024 chunks (2/thread), B 256x64 = 2048 chunks (4/thread)
    const u16* pA[2];
    const u16* pB[4];
    int ldstA[2], ldstB[4];
#pragma unroll
    for (int s = 0; s < 2; ++s) {
        int li = s * 512 + tid;
        int r = li >> 3;
        int g = li & 7;
        int gs = g ^ (r & 7);
        pA[s] = A + (size_t)(row0 + r) * 512 + gs * 8;
        ldstA[s] = li * 8;                       // As at [0, 8192) u16
    }
#pragma unroll
    for (int s = 0; s < 4; ++s) {
        int li = s * 512 + tid;
        int r = li >> 3;
        int g = li & 7;
        int gs = g ^ (r & 7);
        pB[s] = B2T + (size_t)r * 512 + gs * 8;
        ldstB[s] = 8192 + li * 8;                // Bs at [8192, 24576) u16
    }

    // ---- gemm2: 2-phase K-loop, K2 = 512 ----
    for (int kt = 0; kt < 8; ++kt) {
        int k0 = kt << 6;
#pragma unroll
        for (int s = 0; s < 2; ++s) load_lds16(pA[s] + k0, &lds[ldstA[s]]);
#pragma unroll
        for (int s = 0; s < 4; ++s) load_lds16(pB[s] + k0, &lds[ldstB[s]]);
        __syncthreads();
#pragma unroll
        for (int ks = 0; ks < 2; ++ks) {
            int gidx = ks * 4 + q;
            short8 af[4], bg[4];
#pragma unroll
            for (int i = 0; i < 4; ++i) {
                int row = wr + i * 16 + l15;                 // 0..127
                af[i] = *(const short8*)&lds[row * 64 + ((gidx ^ (row & 7)) << 3)];
            }
#pragma unroll
            for (int j = 0; j < 4; ++j) {
                int brow = wc + j * 16 + l15;                // 0..255
                bg[j] = *(const short8*)&lds[8192 + brow * 64 + ((gidx ^ (brow & 7)) << 3)];
            }
#pragma unroll
            for (int i = 0; i < 4; ++i)
#pragma unroll
                for (int j = 0; j < 4; ++j)
                    acc[i][j] = __builtin_amdgcn_mfma_f32_16x16x32_bf16(bg[j], af[i], acc[i][j], 0, 0, 0);
        }
        __syncthreads();
    }

    // ---- h2 tile (gelu(acc+b2), bf16) -> LDS overlay [128][256], XOR-swizzled ----
#pragma unroll
    for (int i = 0; i < 4; ++i) {
        int row = wr + i * 16 + l15;             // 0..127
#pragma unroll
        for (int j = 0; j < 4; ++j) {
            int c = wc + j * 16 + q * 4;         // 0..255
            float4 b4 = *(const float4*)&b2v[c];
            float v0 = gelu_f(acc[i][j][0] + b4.x);
            float v1 = gelu_f(acc[i][j][1] + b4.y);
            float v2 = gelu_f(acc[i][j][2] + b4.z);
            float v3 = gelu_f(acc[i][j][3] + b4.w);
            uint2 pk;
            pk.x = (u32)f2b(v0) | ((u32)f2b(v1) << 16);
            pk.y = (u32)f2b(v2) | ((u32)f2b(v3) << 16);
            int gr = c >> 3;                     // k-granule 0..31
            int addr = row * 256 + ((gr ^ (row & 7)) << 3) + (q & 1) * 4;
            *(uint2*)&lds[addr] = pk;
        }
    }
    __syncthreads();

    // ---- gemm3: h3 = h2 @ W3 + b3, A stationary in LDS, B from global (L2) ----
#pragma unroll
    for (int i = 0; i < 4; ++i)
#pragma unroll
        for (int j = 0; j < 4; ++j)
            acc[i][j] = (floatx4){0.f, 0.f, 0.f, 0.f};

    for (int ks = 0; ks < 8; ++ks) {             // K3 = 256
        int gidx = ks * 4 + q;
        short8 af[4], bg[4];
#pragma unroll
        for (int j = 0; j < 4; ++j) {
            int colr = wc + j * 16 + l15;        // 0..255
            bg[j] = *(const short8*)&W3T[(size_t)colr * 256 + gidx * 8];
        }
#pragma unroll
        for (int i = 0; i < 4; ++i) {
            int row = wr + i * 16 + l15;         // 0..127
            af[i] = *(const short8*)&lds[row * 256 + ((gidx ^ (row & 7)) << 3)];
        }
        __builtin_amdgcn_s_setprio(1);
#pragma unroll
        for (int i = 0; i < 4; ++i)
#pragma unroll
            for (int j = 0; j < 4; ++j)
                acc[i][j] = __builtin_amdgcn_mfma_f32_16x16x32_bf16(bg[j], af[i], acc[i][j], 0, 0, 0);
        __builtin_amdgcn_s_setprio(0);
    }
    __syncthreads();   // all h2 LDS reads done before overwrite

    // ---- h3 tile (bf16) -> LDS [128][256], XOR-swizzled by row&31 ----
#pragma unroll
    for (int i = 0; i < 4; ++i) {
        int row = wr + i * 16 + l15;
#pragma unroll
        for (int j = 0; j < 4; ++j) {
            int c = wc + j * 16 + q * 4;
            float4 b4 = *(const float4*)&b3v[c];
            float v0 = acc[i][j][0] + b4.x;
            float v1 = acc[i][j][1] + b4.y;
            float v2 = acc[i][j][2] + b4.z;
            float v3 = acc[i][j][3] + b4.w;
            uint2 pk;
            pk.x = (u32)f2b(v0) | ((u32)f2b(v1) << 16);
            pk.y = (u32)f2b(v2) | ((u32)f2b(v3) << 16);
            int gr = c >> 3;
            int addr = row * 256 + ((gr ^ (row & 31)) << 3) + (q & 1) * 4;
            *(uint2*)&lds[addr] = pk;
        }
    }
    __syncthreads();

    // ---- head: out = tanh(dyt_w*tanh(alpha*gelu(h3@Wo+bo))+dyt_b), scatter ----
    {
        int r = tid >> 2;                        // 4 threads per row (128 rows)
        int cq = (tid & 3) * 2;                  // channels [cq, cq+2)
        int n = row0 + r;
        int lo = 0, hi = NUM_GRAPHS;
        while (hi - lo > 1) {                    // largest g with soff[g] <= n
            int mid = (lo + hi) >> 1;
            if (soff[mid] <= n) lo = mid; else hi = mid;
        }
        int g = lo;
        int p = n - soff[g];
        float a0 = bo[cq], a1 = bo[cq + 1];
#pragma unroll 4
        for (int kk = 0; kk < 32; ++kk) {        // k = kk*8+e ascending (head_k order)
            short8 h = *(const short8*)&lds[r * 256 + ((kk ^ (r & 31)) << 3)];
#pragma unroll
            for (int e = 0; e < 8; ++e) {
                float hv = __uint_as_float((u32)(u16)h[e] << 16);
                const float* w = &sWo[(kk * 8 + e) * 8 + cq];
                a0 += hv * w[0];
                a1 += hv * w[1];
            }
        }
        float alpha = alpha_p[0];
        float av[2] = {a0, a1};
        float rv[2];
#pragma unroll
        for (int c = 0; c < 2; ++c) {
            float a = gelu_f(av[c]);
            a = dyt_w[cq + c] * tanh_f(alpha * a) + dyt_b[cq + c];
            rv[c] = tanh_f(a);
        }
        *(float2*)&out[((size_t)(p * NUM_GRAPHS + g)) * 8 + cq] = make_float2(rv[0], rv[1]);
    }
}

extern "C" void kernel_launch(void* const* d_in, const int* in_sizes, int n_in,
                              void* d_out, int out_size, void* d_ws, size_t ws_size,
                              hipStream_t stream) {
    (void)in_sizes; (void)n_in; (void)out_size; (void)ws_size;
    const float* x_res = (const float*)d_in[0];
    const int*   batch = (const int*)d_in[1];
    const float* gamma = (const float*)d_in[2];
    const float* beta  = (const float*)d_in[3];
    const float* W1    = (const float*)d_in[4];
    const float* b1    = (const float*)d_in[5];
    const float* W2    = (const float*)d_in[6];
    const float* b2    = (const float*)d_in[7];
    const float* W3    = (const float*)d_in[8];
    const float* b3    = (const float*)d_in[9];
    const float* Wo    = (const float*)d_in[10];
    const float* bo    = (const float*)d_in[11];
    const float* alpha = (const float*)d_in[12];
    const float* dyt_w = (const float*)d_in[13];
    const float* dyt_b = (const float*)d_in[14];
    float* out = (float*)d_out;

    char* ws = (char*)d_ws;
    float* scale = (float*)(ws + 0);
    float* shift = (float*)(ws + 2048);
    float* b1f   = (float*)(ws + 4096);
    int*   offs  = (int*)(ws + 8192);
    u16* W1T = (u16*)(ws + 16384);                       // 512KB
    u16* W2T = (u16*)(ws + 16384 + 524288);              // 256KB
    u16* W3T = (u16*)(ws + 16384 + 524288 + 262144);     // 128KB
    const size_t MB = 1024 * 1024;
    u16* xb = (u16*)(ws + 2 * MB);              // 64MB  [2,66)
    u16* h1 = (u16*)(ws + 66 * MB);             // 64MB  [66,130)
    float4* partials = (float4*)(ws + 66 * MB); // 8MB   (aliases h1; dead before GEMM1)

    statscast_k<<<BN_BLOCKS, 256, 0, stream>>>(x_res, xb, partials);
    bn_reduce_k<<<256, 256, 0, stream>>>(partials, gamma, beta, scale, shift);
    prep_k<<<2306, 256, 0, stream>>>(W1, W2, W3, b1, scale, shift,
                                     W1T, W2T, W3T, b1f, batch, offs,
                                     bo, alpha, dyt_w, dyt_b, out);
    gemm_bt_k<1, 4><<<1024, 512, 0, stream>>>(xb, W1T, b1f, h1, 512, 512);
    gemm23h_k<<<512, 512, 0, stream>>>(h1, W2T, b2, W3T, b3, Wo, bo, offs,
                                       alpha, dyt_w, dyt_b, out);
}